// Round 17
// baseline (668.390 us; speedup 1.0000x reference)
//
#include <hip/hip_runtime.h>
#include <hip/hip_bf16.h>
#include <math.h>

#define NEG_SLOPE 0.2f

static const int NN = 100000;    // nodes per branch
static const int EE = 1600000;   // edges per branch
static const int BB = 512;       // graphs
static const int NTOT = 2 * NN;  // 200000 combined nodes
static const int ETOT = 2 * EE;  // 3200000 combined edges
static const int NBUK = (NTOT + 511) / 512;        // 391 buckets of 512 nodes
static const int CHUNK = 4096;                     // edges per bin-sort block
static const int NBLK = (ETOT + CHUNK - 1) / CHUNK;  // 782 chunks
static const int GB = (NN + 63) / 64;              // 1563 gemm blocks per branch

typedef __attribute__((ext_vector_type(8))) short bf16x8;
typedef __attribute__((ext_vector_type(4))) float f32x4;
typedef __attribute__((ext_vector_type(2))) float f32x2;

__device__ __forceinline__ float leaky(float x) { return x >= 0.f ? x : NEG_SLOPE * x; }

__device__ __forceinline__ unsigned short f2b(float f) {
    __hip_bfloat16 h = __float2bfloat16(f);   // RNE
    return *reinterpret_cast<unsigned short*>(&h);
}
__device__ __forceinline__ float b2f_lo(unsigned v) { return __uint_as_float(v << 16); }
__device__ __forceinline__ float b2f_hi(unsigned v) { return __uint_as_float(v & 0xFFFF0000u); }
__device__ __forceinline__ unsigned packb(float a, float b) {
    return (unsigned)f2b(a) | ((unsigned)f2b(b) << 16);
}
__device__ __forceinline__ void pkfma(f32x2& acc, f32x2 h, f32x2 w) {
    asm("v_pk_fma_f32 %0, %1, %2, %0" : "+v"(acc) : "v"(h), "v"(w));
}
__device__ __forceinline__ f32x2 unpk(unsigned v) {
    f32x2 r;
    r.x = b2f_lo(v);
    r.y = b2f_hi(v);
    return r;
}

// async global -> LDS, 16B per lane (wave-uniform LDS base + lane*16)
__device__ __forceinline__ void gload_lds16(const void* g, void* l) {
    __builtin_amdgcn_global_load_lds(
        (const __attribute__((address_space(1))) void*)g,
        (__attribute__((address_space(3))) void*)l, 16, 0, 0);
}

// ---------------- both W^T casts in one kernel ----------------
__global__ void wt_all_kernel(const float* __restrict__ Ws1, const float* __restrict__ Wt1,
                              const float* __restrict__ Ws2, const float* __restrict__ Wt2_,
                              unsigned short* __restrict__ WT1, unsigned short* __restrict__ WT2) {
    int idx = blockIdx.x * blockDim.x + threadIdx.x;
    if (idx < 2 * 256 * 128) {
        int br = idx >= 256 * 128;
        int j = idx - br * 256 * 128;
        int n = j / 256, k = j - n * 256;
        const float* W = br ? Wt1 : Ws1;
        WT1[idx] = f2b(W[(size_t)k * 128 + n]);
    } else {
        int x = idx - 2 * 256 * 128;
        if (x >= 2 * 128 * 64) return;
        int br = x >= 128 * 64;
        int j = x - br * 128 * 64;
        int n = j / 128, k = j - n * 128;
        const float* W = br ? Wt2_ : Ws2;
        WT2[x] = f2b(W[(size_t)k * 64 + n]);
    }
}

// ================== fused dispatch A: bin_sort blocks + layer-1 GEMM blocks ==========
__device__ __forceinline__ void bin_body(int b, unsigned char* smem,
                                         const int* __restrict__ src_s, const int* __restrict__ dst_s,
                                         const int* __restrict__ src_t, const int* __restrict__ dst_t,
                                         uint2* __restrict__ region, int* __restrict__ shist) {
    int* hist = (int*)smem;            // 512
    int* part = hist + 512;            // 256
    int* cur = part + 256;             // 512
    uint2* lbuf = (uint2*)(smem + 5120);  // 4096
    const int t = threadIdx.x;
    const int base = b * CHUNK;
    const int cnt = min(CHUNK, ETOT - base);
    hist[t] = 0; hist[t + 256] = 0;
    __syncthreads();
    unsigned es[16], ed[16];
    #pragma unroll
    for (int i = 0; i < 16; i++) {
        int li = i * 256 + t;
        if (li < cnt) {
            int e = base + li;
            if (e < EE) {
                es[i] = (unsigned)src_s[e];
                ed[i] = (unsigned)dst_s[e];
            } else {
                es[i] = (unsigned)src_t[e - EE] + NN;
                ed[i] = (unsigned)dst_t[e - EE] + NN;
            }
            atomicAdd(&hist[ed[i] >> 9], 1);
        }
    }
    __syncthreads();
    int d0 = hist[2 * t], d1 = hist[2 * t + 1];
    int s = d0 + d1;
    part[t] = s;
    __syncthreads();
    for (int off = 1; off < 256; off <<= 1) {
        int u = (t >= off) ? part[t - off] : 0;
        __syncthreads();
        part[t] += u;
        __syncthreads();
    }
    int ex = part[t] - s;
    cur[2 * t] = ex;
    cur[2 * t + 1] = ex + d0;
    if (2 * t < NBUK + 1) shist[(2 * t) * NBLK + b] = ex;
    if (2 * t + 1 < NBUK + 1) shist[(2 * t + 1) * NBLK + b] = ex + d0;
    __syncthreads();
    #pragma unroll
    for (int i = 0; i < 16; i++) {
        int li = i * 256 + t;
        if (li < cnt) {
            int slot = atomicAdd(&cur[ed[i] >> 9], 1);
            lbuf[slot] = make_uint2(es[i], ed[i]);
        }
    }
    __syncthreads();
    for (int i = t; i < cnt; i += 256) region[base + i] = lbuf[i];
}

// layer-1 GEMM body: K=256, N=128, f32 A, LDS-staged via global_load_lds + XOR swizzle
__device__ __forceinline__ void gemm1_body(int bid, unsigned char* smem,
                                           const float* __restrict__ Av_s, const float* __restrict__ Av_t,
                                           const unsigned short* __restrict__ WT,
                                           const float* __restrict__ as_s, const float* __restrict__ ad_s,
                                           const float* __restrict__ as_t, const float* __restrict__ ad_t,
                                           unsigned* __restrict__ hb,
                                           float* __restrict__ al_s, float* __restrict__ al_d) {
    constexpr int K = 256, N = 128;
    constexpr int NT2 = 4;
    constexpr int ROWB = 512;
    constexpr int CPR = 32;
    constexpr int IPW = 8;
    constexpr int SWZ = 15;
    constexpr int KBH = 4;

    unsigned char* Atile = smem;                 // 32768
    float* als0 = (float*)(smem + 32768);        // 64
    float* ald0 = als0 + 64;                     // 64

    const int br = (bid >= GB) ? 1 : 0;
    const int lb = bid - br * GB;
    const int t = threadIdx.x;
    const int l = t & 63, w = t >> 6;
    const int wm = w >> 1, wn = w & 1;
    const int rl = l & 15, kh = l >> 4;
    const int row0blk = lb * 64;
    const char* Ab = (const char*)(br ? Av_t : Av_s);
    const unsigned short* WTb = WT + (size_t)br * N * K;
    const float* asv = br ? as_t : as_s;
    const float* adv = br ? ad_t : ad_s;

    f32x4 acc[2][NT2];
    #pragma unroll
    for (int g = 0; g < 2; g++)
        #pragma unroll
        for (int q = 0; q < NT2; q++) acc[g][q] = (f32x4){0.f, 0.f, 0.f, 0.f};

    #pragma unroll
    for (int h = 0; h < 2; h++) {
        #pragma unroll
        for (int i = 0; i < IPW; i++) {
            int c = (i * 4 + w) * 64 + l;
            int row = c / CPR, jp = c % CPR;
            int jg = jp ^ (row & SWZ);
            int rowg = min(row0blk + row, NN - 1);
            const char* src = Ab + ((size_t)rowg * K + h * (K / 2)) * 4 + jg * 16;
            gload_lds16(src, Atile + c * 16);
        }
        bf16x8 Bv[KBH * NT2];
        #pragma unroll
        for (int kb = 0; kb < KBH; kb++)
            #pragma unroll
            for (int q = 0; q < NT2; q++) {
                int c = wn * (N / 2) + q * 16 + rl;
                Bv[kb * NT2 + q] =
                    *(const bf16x8*)(WTb + (size_t)c * K + h * (K / 2) + kb * 32 + kh * 8);
            }
        __syncthreads();
        #pragma unroll
        for (int kb = 0; kb < KBH; kb++) {
            bf16x8 av[2];
            #pragma unroll
            for (int rg = 0; rg < 2; rg++) {
                int r = wm * 32 + rg * 16 + rl;
                int j0 = kb * 8 + kh * 2;
                int j0s = j0 ^ (r & SWZ);
                int j1s = (j0 + 1) ^ (r & SWZ);
                float4 fa = *(const float4*)(Atile + r * ROWB + j0s * 16);
                float4 fb = *(const float4*)(Atile + r * ROWB + j1s * 16);
                union { bf16x8 v; unsigned short u[8]; } au;
                au.u[0] = f2b(fa.x); au.u[1] = f2b(fa.y);
                au.u[2] = f2b(fa.z); au.u[3] = f2b(fa.w);
                au.u[4] = f2b(fb.x); au.u[5] = f2b(fb.y);
                au.u[6] = f2b(fb.z); au.u[7] = f2b(fb.w);
                av[rg] = au.v;
            }
            #pragma unroll
            for (int q = 0; q < NT2; q++) {
                acc[0][q] = __builtin_amdgcn_mfma_f32_16x16x32_bf16(av[0], Bv[kb * NT2 + q], acc[0][q], 0, 0, 0);
                acc[1][q] = __builtin_amdgcn_mfma_f32_16x16x32_bf16(av[1], Bv[kb * NT2 + q], acc[1][q], 0, 0, 0);
            }
        }
        __syncthreads();
    }

    float asr[NT2], adr[NT2];
    #pragma unroll
    for (int q = 0; q < NT2; q++) {
        int c = wn * (N / 2) + q * 16 + rl;
        asr[q] = asv[c];
        adr[q] = adv[c];
    }

    float psA[2][4], pdA[2][4];
    #pragma unroll
    for (int rg = 0; rg < 2; rg++) {
        #pragma unroll
        for (int i = 0; i < 4; i++) {
            float ps = 0.f, pd = 0.f;
            #pragma unroll
            for (int q = 0; q < NT2; q++) {
                float v = acc[rg][q][i];
                ps += v * asr[q];
                pd += v * adr[q];
            }
            #pragma unroll
            for (int off = 1; off < 16; off <<= 1) {
                ps += __shfl_xor(ps, off);
                pd += __shfl_xor(pd, off);
            }
            psA[rg][i] = ps;
            pdA[rg][i] = pd;
        }
    }
    if (wn == 0 && rl == 0) {
        #pragma unroll
        for (int rg = 0; rg < 2; rg++)
            #pragma unroll
            for (int i = 0; i < 4; i++) {
                int rloc = wm * 32 + rg * 16 + kh * 4 + i;
                als0[rloc] = psA[rg][i];
                ald0[rloc] = pdA[rg][i];
            }
    }
    __syncthreads();
    if (wn == 1 && rl == 0) {
        #pragma unroll
        for (int rg = 0; rg < 2; rg++)
            #pragma unroll
            for (int i = 0; i < 4; i++) {
                int rloc = wm * 32 + rg * 16 + kh * 4 + i;
                int rlocal = lb * 64 + rloc;
                if (rlocal < NN) {
                    int g = br * NN + rlocal;
                    al_s[g] = psA[rg][i] + als0[rloc];
                    al_d[g] = pdA[rg][i] + ald0[rloc];
                }
            }
    }
    #pragma unroll
    for (int rg = 0; rg < 2; rg++) {
        #pragma unroll
        for (int i = 0; i < 4; i++) {
            int rlocal = lb * 64 + wm * 32 + rg * 16 + kh * 4 + i;
            bool ok = (rlocal < NN);
            int g = br * NN + rlocal;
            #pragma unroll
            for (int q = 0; q < NT2; q++) {
                float v = acc[rg][q][i];
                float hi = __shfl_xor(v, 1);
                if (ok && !(rl & 1)) {
                    int c = wn * (N / 2) + q * 16 + rl;
                    hb[(size_t)g * (N / 2) + (c >> 1)] = packb(v, hi);
                }
            }
        }
    }
}

__global__ __launch_bounds__(256, 3) void gemm1_bin_kernel(
        const float* __restrict__ Av_s, const float* __restrict__ Av_t,
        const unsigned short* __restrict__ WT,
        const float* __restrict__ as_s, const float* __restrict__ ad_s,
        const float* __restrict__ as_t, const float* __restrict__ ad_t,
        unsigned* __restrict__ hb, float* __restrict__ al_s, float* __restrict__ al_d,
        const int* __restrict__ src_s, const int* __restrict__ dst_s,
        const int* __restrict__ src_t, const int* __restrict__ dst_t,
        uint2* __restrict__ region, int* __restrict__ shist) {
    __shared__ __align__(16) unsigned char smem[38912];
    int bid = blockIdx.x;
    if (bid < NBLK) {
        bin_body(bid, smem, src_s, dst_s, src_t, dst_t, region, shist);
    } else {
        gemm1_body(bid - NBLK, smem, Av_s, Av_t, WT, as_s, ad_s, as_t, ad_t, hb, al_s, al_d);
    }
}

// ---- layer-2 GEMM (bf16 A), standalone ----
template <int K, int N>
__global__ __launch_bounds__(256, 3) void gemm2_kernel(
        const unsigned short* __restrict__ Ab_s, const unsigned short* __restrict__ Ab_t,
        const unsigned short* __restrict__ WT,
        const float* __restrict__ as_s, const float* __restrict__ ad_s,
        const float* __restrict__ as_t, const float* __restrict__ ad_t,
        unsigned* __restrict__ hb, float* __restrict__ al_s, float* __restrict__ al_d,
        int nblk) {
    constexpr int NT2 = N / 32;
    constexpr int ROWB = (K / 2) * 2;
    constexpr int CPR = ROWB / 16;
    constexpr int STB = 64 * ROWB;
    constexpr int IPW = (STB / 16) / 256;
    constexpr int SWZ = (CPR - 1) < 15 ? (CPR - 1) : 15;
    constexpr int KBH = (K / 2) / 32;

    __shared__ __align__(16) unsigned char Atile[STB];
    __shared__ float als0[64], ald0[64];

    const int bid = blockIdx.x;
    const int br = (bid >= nblk) ? 1 : 0;
    const int lb = bid - br * nblk;
    const int t = threadIdx.x;
    const int l = t & 63, w = t >> 6;
    const int wm = w >> 1, wn = w & 1;
    const int rl = l & 15, kh = l >> 4;
    const int row0blk = lb * 64;
    const char* Ab = (const char*)(br ? Ab_t : Ab_s);
    const unsigned short* WTb = WT + (size_t)br * N * K;
    const float* asv = br ? as_t : as_s;
    const float* adv = br ? ad_t : ad_s;

    f32x4 acc[2][NT2];
    #pragma unroll
    for (int g = 0; g < 2; g++)
        #pragma unroll
        for (int q = 0; q < NT2; q++) acc[g][q] = (f32x4){0.f, 0.f, 0.f, 0.f};

    #pragma unroll
    for (int h = 0; h < 2; h++) {
        #pragma unroll
        for (int i = 0; i < IPW; i++) {
            int c = (i * 4 + w) * 64 + l;
            int row = c / CPR, jp = c % CPR;
            int jg = jp ^ (row & SWZ);
            int rowg = min(row0blk + row, NN - 1);
            const char* src = Ab + ((size_t)rowg * K + h * (K / 2)) * 2 + jg * 16;
            gload_lds16(src, Atile + c * 16);
        }
        bf16x8 Bv[KBH * NT2];
        #pragma unroll
        for (int kb = 0; kb < KBH; kb++)
            #pragma unroll
            for (int q = 0; q < NT2; q++) {
                int c = wn * (N / 2) + q * 16 + rl;
                Bv[kb * NT2 + q] =
                    *(const bf16x8*)(WTb + (size_t)c * K + h * (K / 2) + kb * 32 + kh * 8);
            }
        __syncthreads();
        #pragma unroll
        for (int kb = 0; kb < KBH; kb++) {
            bf16x8 av[2];
            #pragma unroll
            for (int rg = 0; rg < 2; rg++) {
                int r = wm * 32 + rg * 16 + rl;
                int j = kb * 4 + kh;
                int js = j ^ (r & SWZ);
                av[rg] = *(const bf16x8*)(Atile + r * ROWB + js * 16);
            }
            #pragma unroll
            for (int q = 0; q < NT2; q++) {
                acc[0][q] = __builtin_amdgcn_mfma_f32_16x16x32_bf16(av[0], Bv[kb * NT2 + q], acc[0][q], 0, 0, 0);
                acc[1][q] = __builtin_amdgcn_mfma_f32_16x16x32_bf16(av[1], Bv[kb * NT2 + q], acc[1][q], 0, 0, 0);
            }
        }
        __syncthreads();
    }

    float asr[NT2], adr[NT2];
    #pragma unroll
    for (int q = 0; q < NT2; q++) {
        int c = wn * (N / 2) + q * 16 + rl;
        asr[q] = asv[c];
        adr[q] = adv[c];
    }

    float psA[2][4], pdA[2][4];
    #pragma unroll
    for (int rg = 0; rg < 2; rg++) {
        #pragma unroll
        for (int i = 0; i < 4; i++) {
            float ps = 0.f, pd = 0.f;
            #pragma unroll
            for (int q = 0; q < NT2; q++) {
                float v = acc[rg][q][i];
                ps += v * asr[q];
                pd += v * adr[q];
            }
            #pragma unroll
            for (int off = 1; off < 16; off <<= 1) {
                ps += __shfl_xor(ps, off);
                pd += __shfl_xor(pd, off);
            }
            psA[rg][i] = ps;
            pdA[rg][i] = pd;
        }
    }
    if (wn == 0 && rl == 0) {
        #pragma unroll
        for (int rg = 0; rg < 2; rg++)
            #pragma unroll
            for (int i = 0; i < 4; i++) {
                int rloc = wm * 32 + rg * 16 + kh * 4 + i;
                als0[rloc] = psA[rg][i];
                ald0[rloc] = pdA[rg][i];
            }
    }
    __syncthreads();
    if (wn == 1 && rl == 0) {
        #pragma unroll
        for (int rg = 0; rg < 2; rg++)
            #pragma unroll
            for (int i = 0; i < 4; i++) {
                int rloc = wm * 32 + rg * 16 + kh * 4 + i;
                int rlocal = lb * 64 + rloc;
                if (rlocal < NN) {
                    int g = br * NN + rlocal;
                    al_s[g] = psA[rg][i] + als0[rloc];
                    al_d[g] = pdA[rg][i] + ald0[rloc];
                }
            }
    }
    #pragma unroll
    for (int rg = 0; rg < 2; rg++) {
        #pragma unroll
        for (int i = 0; i < 4; i++) {
            int rlocal = lb * 64 + wm * 32 + rg * 16 + kh * 4 + i;
            bool ok = (rlocal < NN);
            int g = br * NN + rlocal;
            #pragma unroll
            for (int q = 0; q < NT2; q++) {
                float v = acc[rg][q][i];
                float hi = __shfl_xor(v, 1);
                if (ok && !(rl & 1)) {
                    int c = wn * (N / 2) + q * 16 + rl;
                    hb[(size_t)g * (N / 2) + (c >> 1)] = packb(v, hi);
                }
            }
        }
    }
}

// per-bucket totals (one block per bucket, coalesced over chunks)
__global__ void bucket_tot_kernel(const int* __restrict__ shist, int* __restrict__ btot) {
    __shared__ int red[256];
    const int k = blockIdx.x, t = threadIdx.x;
    int s = 0;
    for (int b = t; b < NBLK; b += 256)
        s += shist[(k + 1) * NBLK + b] - shist[k * NBLK + b];
    red[t] = s;
    __syncthreads();
    for (int off = 128; off > 0; off >>= 1) {
        if (t < off) red[t] += red[t + off];
        __syncthreads();
    }
    if (t == 0) btot[k] = red[0];
}

// pass B: one block per bucket -> prefix from btot + LDS histogram/scan -> rowptr + col
__global__ __launch_bounds__(256) void csr_bucket_kernel(const uint2* __restrict__ region,
                                                         const int* __restrict__ shist,
                                                         const int* __restrict__ btot,
                                                         int* __restrict__ rowptr,
                                                         int* __restrict__ col) {
    __shared__ int deg[512];
    __shared__ int part[256];
    __shared__ int cur[512];
    const int k = blockIdx.x, t = threadIdx.x;
    const int n0 = k * 512;
    const int nloc = min(512, NTOT - n0);
    // base = sum of btot[i] for i < k (parallel reduce)
    int bacc = 0;
    for (int i = t; i < NBUK; i += 256)
        if (i < k) bacc += btot[i];
    part[t] = bacc;
    deg[t] = 0; deg[t + 256] = 0;
    __syncthreads();
    for (int off = 128; off > 0; off >>= 1) {
        if (t < off) part[t] += part[t + off];
        __syncthreads();
    }
    const int base = part[0];
    __syncthreads();
    // count
    for (int b = t; b < NBLK; b += 256) {
        int s0 = shist[k * NBLK + b], s1 = shist[(k + 1) * NBLK + b];
        for (int i = s0; i < s1; i++) {
            uint2 e = region[(size_t)b * CHUNK + i];
            atomicAdd(&deg[(int)e.y - n0], 1);
        }
    }
    __syncthreads();
    int d0 = deg[2 * t], d1 = deg[2 * t + 1];
    int s = d0 + d1;
    part[t] = s;
    __syncthreads();
    for (int off = 1; off < 256; off <<= 1) {
        int u = (t >= off) ? part[t - off] : 0;
        __syncthreads();
        part[t] += u;
        __syncthreads();
    }
    int ex = part[t] - s;
    cur[2 * t] = ex;
    cur[2 * t + 1] = ex + d0;
    if (2 * t < nloc) rowptr[n0 + 2 * t] = base + ex;
    if (2 * t + 1 < nloc) rowptr[n0 + 2 * t + 1] = base + ex + d0;
    if (t == 0 && n0 + nloc == NTOT) rowptr[NTOT] = base + part[255];
    __syncthreads();
    // place
    for (int b = t; b < NBLK; b += 256) {
        int s0 = shist[k * NBLK + b], s1 = shist[(k + 1) * NBLK + b];
        for (int i = s0; i < s1; i++) {
            uint2 e = region[(size_t)b * CHUNK + i];
            int pos = atomicAdd(&cur[(int)e.y - n0], 1);
            col[base + pos] = (int)e.x;
        }
    }
}

// ---------------- GAT aggregate, D=128: 8 edges/wave-pass, packed-f32 accumulate ------
__global__ void gat_gather128_kernel(const int* __restrict__ rowptr, const int* __restrict__ col,
                                     const float* __restrict__ al_s, const float* __restrict__ al_d,
                                     const unsigned* __restrict__ hb,
                                     const float* __restrict__ bias_s,
                                     const float* __restrict__ bias_t,
                                     unsigned* __restrict__ outb) {
    int node = blockIdx.x * 4 + (threadIdx.x >> 6);
    int lane = threadIdx.x & 63;
    if (node >= NTOT) return;
    const float* bias = (node < NN) ? bias_s : bias_t;
    const int slot = lane >> 4, sub = lane & 15;
    const int beg = rowptr[node], end = rowptr[node + 1];
    const float ald = al_d[node];
    const float e_self = leaky(al_s[node] + ald);

    f32x2 acc2[4];
    #pragma unroll
    for (int k = 0; k < 4; k++) acc2[k] = (f32x2){0.f, 0.f};
    float dsum = 0.f;
    for (int base = beg; base < end; base += 64) {
        int i = base + lane;
        float w = 0.f; int s = 0;
        if (i < end) {
            s = col[i];
            w = expf(leaky(al_s[s] + ald));   // no max shift: |e| small, f32-safe
        }
        dsum += w;
        int cnt = min(64, end - base);
        for (int j = 0; j < cnt; j += 8) {
            int idx0 = j + slot, idx1 = j + 4 + slot;
            float w0 = __shfl(w, idx0), w1 = __shfl(w, idx1);
            int s0 = __shfl(s, idx0), s1 = __shfl(s, idx1);
            uint4 v0 = *(const uint4*)(hb + (size_t)s0 * 64 + sub * 4);
            uint4 v1 = *(const uint4*)(hb + (size_t)s1 * 64 + sub * 4);
            f32x2 wp0 = (f32x2){w0, w0}, wp1 = (f32x2){w1, w1};
            pkfma(acc2[0], unpk(v0.x), wp0);
            pkfma(acc2[1], unpk(v0.y), wp0);
            pkfma(acc2[2], unpk(v0.z), wp0);
            pkfma(acc2[3], unpk(v0.w), wp0);
            pkfma(acc2[0], unpk(v1.x), wp1);
            pkfma(acc2[1], unpk(v1.y), wp1);
            pkfma(acc2[2], unpk(v1.z), wp1);
            pkfma(acc2[3], unpk(v1.w), wp1);
        }
    }
    float acc[8];
    #pragma unroll
    for (int k = 0; k < 4; k++) { acc[2 * k] = acc2[k].x; acc[2 * k + 1] = acc2[k].y; }
    #pragma unroll
    for (int k = 0; k < 8; k++) {
        acc[k] += __shfl_xor(acc[k], 16);
        acc[k] += __shfl_xor(acc[k], 32);
    }
    #pragma unroll
    for (int off = 32; off > 0; off >>= 1) dsum += __shfl_xor(dsum, off);

    float wself = expf(e_self);
    dsum += wself;
    float inv = 1.f / dsum;
    if (slot == 0) {
        uint4 sv = *(const uint4*)(hb + (size_t)node * 64 + sub * 4);
        float sf[8] = { b2f_lo(sv.x), b2f_hi(sv.x), b2f_lo(sv.y), b2f_hi(sv.y),
                        b2f_lo(sv.z), b2f_hi(sv.z), b2f_lo(sv.w), b2f_hi(sv.w) };
        float o[8];
        #pragma unroll
        for (int k = 0; k < 8; k++)
            o[k] = bias[sub * 8 + k] + (acc[k] + wself * sf[k]) * inv;
        uint4 r = make_uint4(packb(o[0], o[1]), packb(o[2], o[3]),
                             packb(o[4], o[5]), packb(o[6], o[7]));
        *(uint4*)(outb + (size_t)node * 64 + sub * 4) = r;
    }
}

// ---- GAT aggregate D=64 + fused mean-pool accumulation (atomic sums; mean in final) --
__global__ void gat_gather64_kernel(const int* __restrict__ rowptr, const int* __restrict__ col,
                                    const float* __restrict__ al_s, const float* __restrict__ al_d,
                                    const unsigned* __restrict__ hb,
                                    const float* __restrict__ bias_s,
                                    const float* __restrict__ bias_t,
                                    const int* __restrict__ bs, const int* __restrict__ bt,
                                    float* __restrict__ pooled_s, float* __restrict__ pooled_t) {
    int node = blockIdx.x * 4 + (threadIdx.x >> 6);
    int lane = threadIdx.x & 63;
    if (node >= NTOT) return;
    const float* bias = (node < NN) ? bias_s : bias_t;
    const int slot = lane >> 4, sub = lane & 15;
    const int beg = rowptr[node], end = rowptr[node + 1];
    const float ald = al_d[node];
    const float e_self = leaky(al_s[node] + ald);

    f32x2 acc2[2];
    acc2[0] = (f32x2){0.f, 0.f};
    acc2[1] = (f32x2){0.f, 0.f};
    float dsum = 0.f;
    for (int base = beg; base < end; base += 64) {
        int i = base + lane;
        float w = 0.f; int s = 0;
        if (i < end) {
            s = col[i];
            w = expf(leaky(al_s[s] + ald));
        }
        dsum += w;
        int cnt = min(64, end - base);
        for (int j = 0; j < cnt; j += 8) {
            int idx0 = j + slot, idx1 = j + 4 + slot;
            float w0 = __shfl(w, idx0), w1 = __shfl(w, idx1);
            int s0 = __shfl(s, idx0), s1 = __shfl(s, idx1);
            uint2 v0 = *(const uint2*)(hb + (size_t)s0 * 32 + sub * 2);
            uint2 v1 = *(const uint2*)(hb + (size_t)s1 * 32 + sub * 2);
            f32x2 wp0 = (f32x2){w0, w0}, wp1 = (f32x2){w1, w1};
            pkfma(acc2[0], unpk(v0.x), wp0);
            pkfma(acc2[1], unpk(v0.y), wp0);
            pkfma(acc2[0], unpk(v1.x), wp1);
            pkfma(acc2[1], unpk(v1.y), wp1);
        }
    }
    float acc[4] = { acc2[0].x, acc2[0].y, acc2[1].x, acc2[1].y };
    #pragma unroll
    for (int k = 0; k < 4; k++) {
        acc[k] += __shfl_xor(acc[k], 16);
        acc[k] += __shfl_xor(acc[k], 32);
    }
    #pragma unroll
    for (int off = 32; off > 0; off >>= 1) dsum += __shfl_xor(dsum, off);

    float wself = expf(e_self);
    dsum += wself;
    float inv = 1.f / dsum;
    if (slot == 0) {
        uint2 sv = *(const uint2*)(hb + (size_t)node * 32 + sub * 2);
        float sf[4] = { b2f_lo(sv.x), b2f_hi(sv.x), b2f_lo(sv.y), b2f_hi(sv.y) };
        int nid = (node < NN) ? node : node - NN;
        const int* batch = (node < NN) ? bs : bt;
        float* pooled = (node < NN) ? pooled_s : pooled_t;
        int g = batch[nid];
        float* pp = pooled + (size_t)g * 64 + sub * 4;
        atomicAdd(pp + 0, bias[sub * 4 + 0] + (acc[0] + wself * sf[0]) * inv);
        atomicAdd(pp + 1, bias[sub * 4 + 1] + (acc[1] + wself * sf[1]) * inv);
        atomicAdd(pp + 2, bias[sub * 4 + 2] + (acc[2] + wself * sf[2]) * inv);
        atomicAdd(pp + 3, bias[sub * 4 + 3] + (acc[3] + wself * sf[3]) * inv);
    }
}

// ---------------- final: mean + sigmoid((xs+xt)@lin_w + lin_b) ----------------
__global__ void final_kernel(const float* __restrict__ ps, const float* __restrict__ pt,
                             const int* __restrict__ bs, const int* __restrict__ bt,
                             const float* __restrict__ lw, const float* __restrict__ lb,
                             float* __restrict__ out) {
    __shared__ int bnd[4];
    int g = blockIdx.x;
    int tid = threadIdx.x;
    if (tid < 4) {
        const int* batch = (tid < 2) ? bs : bt;
        int target = g + (tid & 1);
        int lo = 0, hi = NN;
        while (lo < hi) {
            int mid = (lo + hi) >> 1;
            if (batch[mid] < target) lo = mid + 1; else hi = mid;
        }
        bnd[tid] = lo;
    }
    __syncthreads();
    if (tid >= 27) return;
    float ics = 1.f / fmaxf((float)(bnd[1] - bnd[0]), 1.f);
    float ict = 1.f / fmaxf((float)(bnd[3] - bnd[2]), 1.f);
    float acc = lb[tid];
    #pragma unroll 8
    for (int k = 0; k < 64; k++) {
        float xv = ps[g * 64 + k] * ics + pt[g * 64 + k] * ict;
        acc += xv * lw[k * 27 + tid];
    }
    out[g * 27 + tid] = 1.f / (1.f + expf(-acc));
}

extern "C" void kernel_launch(void* const* d_in, const int* in_sizes, int n_in,
                              void* d_out, int out_size, void* d_ws, size_t ws_size,
                              hipStream_t stream) {
    const float* x_s = (const float*)d_in[0];
    const float* x_t = (const float*)d_in[1];
    const int* ei_s = (const int*)d_in[2];
    const int* ei_t = (const int*)d_in[3];
    const int* xs_batch = (const int*)d_in[4];
    const int* xt_batch = (const int*)d_in[5];
    const float* W_s1 = (const float*)d_in[6];
    const float* a_src_s1 = (const float*)d_in[7];
    const float* a_dst_s1 = (const float*)d_in[8];
    const float* b_s1 = (const float*)d_in[9];
    const float* W_s2 = (const float*)d_in[10];
    const float* a_src_s2 = (const float*)d_in[11];
    const float* a_dst_s2 = (const float*)d_in[12];
    const float* b_s2 = (const float*)d_in[13];
    const float* W_t1 = (const float*)d_in[14];
    const float* a_src_t1 = (const float*)d_in[15];
    const float* a_dst_t1 = (const float*)d_in[16];
    const float* b_t1 = (const float*)d_in[17];
    const float* W_t2 = (const float*)d_in[18];
    const float* a_src_t2 = (const float*)d_in[19];
    const float* a_dst_t2 = (const float*)d_in[20];
    const float* b_t2 = (const float*)d_in[21];
    const float* lin_w = (const float*)d_in[22];
    const float* lin_b = (const float*)d_in[23];
    float* out = (float*)d_out;

    // workspace carve-up (dword units)
    unsigned* hb = (unsigned*)d_ws;                        // NTOT*64 dw (51.2 MB)
    unsigned* out1b = hb + (size_t)NTOT * 64;              // NTOT*64 dw (51.2 MB)
    uint2* region = (uint2*)(out1b + (size_t)NTOT * 64);   // NBLK*CHUNK uint2 (25.6 MB)
    int* col = (int*)(region + (size_t)NBLK * CHUNK);      // ETOT
    float* al_s = (float*)(col + ETOT);                    // NTOT
    float* al_d = al_s + NTOT;                             // NTOT
    float* pooled_s = al_d + NTOT;                         // BB*64
    float* pooled_t = pooled_s + (size_t)BB * 64;          // BB*64
    unsigned short* WT1 = (unsigned short*)(pooled_t + (size_t)BB * 64);  // 2*128*256
    unsigned short* WT2 = WT1 + 2 * 256 * 128;             // 2*64*128
    int* rowptr = (int*)(WT2 + 2 * 128 * 64);              // NTOT+1
    int* shist = rowptr + NTOT + 1;                        // (NBUK+1)*NBLK
    int* btot = shist + (NBUK + 1) * NBLK;                 // NBUK

    const int* src_s = ei_s;
    const int* dst_s = ei_s + EE;
    const int* src_t = ei_t;
    const int* dst_t = ei_t + EE;

    // zero pooled accumulators (atomically accumulated by gather64)
    hipMemsetAsync(pooled_s, 0, (size_t)BB * 64 * 2 * sizeof(float), stream);

    // ----- W^T casts (both layers, one kernel) -----
    wt_all_kernel<<<(2 * 256 * 128 + 2 * 128 * 64 + 255) / 256, 256, 0, stream>>>(
        W_s1, W_t1, W_s2, W_t2, WT1, WT2);

    // ----- fused: bin_sort (CSR pass A) + layer-1 GEMM -----
    gemm1_bin_kernel<<<NBLK + 2 * GB, 256, 0, stream>>>(
        x_s, x_t, WT1, a_src_s1, a_dst_s1, a_src_t1, a_dst_t1, hb, al_s, al_d,
        src_s, dst_s, src_t, dst_t, region, shist);

    // ----- CSR pass B -----
    bucket_tot_kernel<<<NBUK, 256, 0, stream>>>(shist, btot);
    csr_bucket_kernel<<<NBUK, 256, 0, stream>>>(region, shist, btot, rowptr, col);

    // ----- layer 1 gather -----
    gat_gather128_kernel<<<(NTOT + 3) / 4, 256, 0, stream>>>(
        rowptr, col, al_s, al_d, hb, b_s1, b_t1, out1b);

    // ----- layer 2 -----
    gemm2_kernel<128, 64><<<2 * GB, 256, 0, stream>>>(
        (const unsigned short*)out1b, (const unsigned short*)out1b + (size_t)NN * 128, WT2,
        a_src_s2, a_dst_s2, a_src_t2, a_dst_t2, hb, al_s, al_d, GB);
    gat_gather64_kernel<<<(NTOT + 3) / 4, 256, 0, stream>>>(
        rowptr, col, al_s, al_d, hb, b_s2, b_t2, xs_batch, xt_batch, pooled_s, pooled_t);

    // ----- head -----
    final_kernel<<<BB, 32, 0, stream>>>(pooled_s, pooled_t, xs_batch, xt_batch, lin_w, lin_b, out);
}

// Round 18
// 449.971 us; speedup vs baseline: 1.4854x; 1.4854x over previous
//
#include <hip/hip_runtime.h>
#include <hip/hip_bf16.h>
#include <math.h>

#define NEG_SLOPE 0.2f

static const int NN = 100000;    // nodes per branch
static const int EE = 1600000;   // edges per branch
static const int BB = 512;       // graphs
static const int NTOT = 2 * NN;  // 200000 combined nodes
static const int ETOT = 2 * EE;  // 3200000 combined edges
static const int NBUK = (NTOT + 511) / 512;        // 391 buckets of 512 nodes
static const int CHUNK = 4096;                     // edges per bin-sort block
static const int NBLK = (ETOT + CHUNK - 1) / CHUNK;  // 782 chunks
static const int GB = (NN + 63) / 64;              // 1563 gemm blocks per branch

typedef __attribute__((ext_vector_type(8))) short bf16x8;
typedef __attribute__((ext_vector_type(4))) float f32x4;
typedef __attribute__((ext_vector_type(2))) float f32x2;

__device__ __forceinline__ float leaky(float x) { return x >= 0.f ? x : NEG_SLOPE * x; }

__device__ __forceinline__ unsigned short f2b(float f) {
    __hip_bfloat16 h = __float2bfloat16(f);   // RNE
    return *reinterpret_cast<unsigned short*>(&h);
}
__device__ __forceinline__ float b2f_lo(unsigned v) { return __uint_as_float(v << 16); }
__device__ __forceinline__ float b2f_hi(unsigned v) { return __uint_as_float(v & 0xFFFF0000u); }
__device__ __forceinline__ unsigned packb(float a, float b) {
    return (unsigned)f2b(a) | ((unsigned)f2b(b) << 16);
}
__device__ __forceinline__ void pkfma(f32x2& acc, f32x2 h, f32x2 w) {
    asm("v_pk_fma_f32 %0, %1, %2, %0" : "+v"(acc) : "v"(h), "v"(w));
}
__device__ __forceinline__ f32x2 unpk(unsigned v) {
    f32x2 r;
    r.x = b2f_lo(v);
    r.y = b2f_hi(v);
    return r;
}

// async global -> LDS, 16B per lane (wave-uniform LDS base + lane*16)
__device__ __forceinline__ void gload_lds16(const void* g, void* l) {
    __builtin_amdgcn_global_load_lds(
        (const __attribute__((address_space(1))) void*)g,
        (__attribute__((address_space(3))) void*)l, 16, 0, 0);
}

// ---------------- both W^T casts in one kernel ----------------
__global__ void wt_all_kernel(const float* __restrict__ Ws1, const float* __restrict__ Wt1,
                              const float* __restrict__ Ws2, const float* __restrict__ Wt2_,
                              unsigned short* __restrict__ WT1, unsigned short* __restrict__ WT2) {
    int idx = blockIdx.x * blockDim.x + threadIdx.x;
    if (idx < 2 * 256 * 128) {
        int br = idx >= 256 * 128;
        int j = idx - br * 256 * 128;
        int n = j / 256, k = j - n * 256;
        const float* W = br ? Wt1 : Ws1;
        WT1[idx] = f2b(W[(size_t)k * 128 + n]);
    } else {
        int x = idx - 2 * 256 * 128;
        if (x >= 2 * 128 * 64) return;
        int br = x >= 128 * 64;
        int j = x - br * 128 * 64;
        int n = j / 128, k = j - n * 128;
        const float* W = br ? Wt2_ : Ws2;
        WT2[x] = f2b(W[(size_t)k * 64 + n]);
    }
}

// ================== fused dispatch A: bin_sort blocks + layer-1 GEMM blocks ==========
__device__ __forceinline__ void bin_body(int b, unsigned char* smem,
                                         const int* __restrict__ src_s, const int* __restrict__ dst_s,
                                         const int* __restrict__ src_t, const int* __restrict__ dst_t,
                                         uint2* __restrict__ region, int* __restrict__ shist) {
    int* hist = (int*)smem;            // 512
    int* part = hist + 512;            // 256
    int* cur = part + 256;             // 512
    uint2* lbuf = (uint2*)(smem + 5120);  // 4096
    const int t = threadIdx.x;
    const int base = b * CHUNK;
    const int cnt = min(CHUNK, ETOT - base);
    hist[t] = 0; hist[t + 256] = 0;
    __syncthreads();
    unsigned es[16], ed[16];
    #pragma unroll
    for (int i = 0; i < 16; i++) {
        int li = i * 256 + t;
        if (li < cnt) {
            int e = base + li;
            if (e < EE) {
                es[i] = (unsigned)src_s[e];
                ed[i] = (unsigned)dst_s[e];
            } else {
                es[i] = (unsigned)src_t[e - EE] + NN;
                ed[i] = (unsigned)dst_t[e - EE] + NN;
            }
            atomicAdd(&hist[ed[i] >> 9], 1);
        }
    }
    __syncthreads();
    int d0 = hist[2 * t], d1 = hist[2 * t + 1];
    int s = d0 + d1;
    part[t] = s;
    __syncthreads();
    for (int off = 1; off < 256; off <<= 1) {
        int u = (t >= off) ? part[t - off] : 0;
        __syncthreads();
        part[t] += u;
        __syncthreads();
    }
    int ex = part[t] - s;
    cur[2 * t] = ex;
    cur[2 * t + 1] = ex + d0;
    if (2 * t < NBUK + 1) shist[(2 * t) * NBLK + b] = ex;
    if (2 * t + 1 < NBUK + 1) shist[(2 * t + 1) * NBLK + b] = ex + d0;
    __syncthreads();
    #pragma unroll
    for (int i = 0; i < 16; i++) {
        int li = i * 256 + t;
        if (li < cnt) {
            int slot = atomicAdd(&cur[ed[i] >> 9], 1);
            lbuf[slot] = make_uint2(es[i], ed[i]);
        }
    }
    __syncthreads();
    for (int i = t; i < cnt; i += 256) region[base + i] = lbuf[i];
}

// layer-1 GEMM body: K=256, N=128, f32 A, LDS-staged via global_load_lds + XOR swizzle
__device__ __forceinline__ void gemm1_body(int bid, unsigned char* smem,
                                           const float* __restrict__ Av_s, const float* __restrict__ Av_t,
                                           const unsigned short* __restrict__ WT,
                                           const float* __restrict__ as_s, const float* __restrict__ ad_s,
                                           const float* __restrict__ as_t, const float* __restrict__ ad_t,
                                           unsigned* __restrict__ hb,
                                           float* __restrict__ al_s, float* __restrict__ al_d) {
    constexpr int K = 256, N = 128;
    constexpr int NT2 = 4;
    constexpr int ROWB = 512;
    constexpr int CPR = 32;
    constexpr int IPW = 8;
    constexpr int SWZ = 15;
    constexpr int KBH = 4;

    unsigned char* Atile = smem;                 // 32768
    float* als0 = (float*)(smem + 32768);        // 64
    float* ald0 = als0 + 64;                     // 64

    const int br = (bid >= GB) ? 1 : 0;
    const int lb = bid - br * GB;
    const int t = threadIdx.x;
    const int l = t & 63, w = t >> 6;
    const int wm = w >> 1, wn = w & 1;
    const int rl = l & 15, kh = l >> 4;
    const int row0blk = lb * 64;
    const char* Ab = (const char*)(br ? Av_t : Av_s);
    const unsigned short* WTb = WT + (size_t)br * N * K;
    const float* asv = br ? as_t : as_s;
    const float* adv = br ? ad_t : ad_s;

    f32x4 acc[2][NT2];
    #pragma unroll
    for (int g = 0; g < 2; g++)
        #pragma unroll
        for (int q = 0; q < NT2; q++) acc[g][q] = (f32x4){0.f, 0.f, 0.f, 0.f};

    #pragma unroll
    for (int h = 0; h < 2; h++) {
        #pragma unroll
        for (int i = 0; i < IPW; i++) {
            int c = (i * 4 + w) * 64 + l;
            int row = c / CPR, jp = c % CPR;
            int jg = jp ^ (row & SWZ);
            int rowg = min(row0blk + row, NN - 1);
            const char* src = Ab + ((size_t)rowg * K + h * (K / 2)) * 4 + jg * 16;
            gload_lds16(src, Atile + c * 16);
        }
        bf16x8 Bv[KBH * NT2];
        #pragma unroll
        for (int kb = 0; kb < KBH; kb++)
            #pragma unroll
            for (int q = 0; q < NT2; q++) {
                int c = wn * (N / 2) + q * 16 + rl;
                Bv[kb * NT2 + q] =
                    *(const bf16x8*)(WTb + (size_t)c * K + h * (K / 2) + kb * 32 + kh * 8);
            }
        __syncthreads();
        #pragma unroll
        for (int kb = 0; kb < KBH; kb++) {
            bf16x8 av[2];
            #pragma unroll
            for (int rg = 0; rg < 2; rg++) {
                int r = wm * 32 + rg * 16 + rl;
                int j0 = kb * 8 + kh * 2;
                int j0s = j0 ^ (r & SWZ);
                int j1s = (j0 + 1) ^ (r & SWZ);
                float4 fa = *(const float4*)(Atile + r * ROWB + j0s * 16);
                float4 fb = *(const float4*)(Atile + r * ROWB + j1s * 16);
                union { bf16x8 v; unsigned short u[8]; } au;
                au.u[0] = f2b(fa.x); au.u[1] = f2b(fa.y);
                au.u[2] = f2b(fa.z); au.u[3] = f2b(fa.w);
                au.u[4] = f2b(fb.x); au.u[5] = f2b(fb.y);
                au.u[6] = f2b(fb.z); au.u[7] = f2b(fb.w);
                av[rg] = au.v;
            }
            #pragma unroll
            for (int q = 0; q < NT2; q++) {
                acc[0][q] = __builtin_amdgcn_mfma_f32_16x16x32_bf16(av[0], Bv[kb * NT2 + q], acc[0][q], 0, 0, 0);
                acc[1][q] = __builtin_amdgcn_mfma_f32_16x16x32_bf16(av[1], Bv[kb * NT2 + q], acc[1][q], 0, 0, 0);
            }
        }
        __syncthreads();
    }

    float asr[NT2], adr[NT2];
    #pragma unroll
    for (int q = 0; q < NT2; q++) {
        int c = wn * (N / 2) + q * 16 + rl;
        asr[q] = asv[c];
        adr[q] = adv[c];
    }

    float psA[2][4], pdA[2][4];
    #pragma unroll
    for (int rg = 0; rg < 2; rg++) {
        #pragma unroll
        for (int i = 0; i < 4; i++) {
            float ps = 0.f, pd = 0.f;
            #pragma unroll
            for (int q = 0; q < NT2; q++) {
                float v = acc[rg][q][i];
                ps += v * asr[q];
                pd += v * adr[q];
            }
            #pragma unroll
            for (int off = 1; off < 16; off <<= 1) {
                ps += __shfl_xor(ps, off);
                pd += __shfl_xor(pd, off);
            }
            psA[rg][i] = ps;
            pdA[rg][i] = pd;
        }
    }
    if (wn == 0 && rl == 0) {
        #pragma unroll
        for (int rg = 0; rg < 2; rg++)
            #pragma unroll
            for (int i = 0; i < 4; i++) {
                int rloc = wm * 32 + rg * 16 + kh * 4 + i;
                als0[rloc] = psA[rg][i];
                ald0[rloc] = pdA[rg][i];
            }
    }
    __syncthreads();
    if (wn == 1 && rl == 0) {
        #pragma unroll
        for (int rg = 0; rg < 2; rg++)
            #pragma unroll
            for (int i = 0; i < 4; i++) {
                int rloc = wm * 32 + rg * 16 + kh * 4 + i;
                int rlocal = lb * 64 + rloc;
                if (rlocal < NN) {
                    int g = br * NN + rlocal;
                    al_s[g] = psA[rg][i] + als0[rloc];
                    al_d[g] = pdA[rg][i] + ald0[rloc];
                }
            }
    }
    #pragma unroll
    for (int rg = 0; rg < 2; rg++) {
        #pragma unroll
        for (int i = 0; i < 4; i++) {
            int rlocal = lb * 64 + wm * 32 + rg * 16 + kh * 4 + i;
            bool ok = (rlocal < NN);
            int g = br * NN + rlocal;
            #pragma unroll
            for (int q = 0; q < NT2; q++) {
                float v = acc[rg][q][i];
                float hi = __shfl_xor(v, 1);
                if (ok && !(rl & 1)) {
                    int c = wn * (N / 2) + q * 16 + rl;
                    hb[(size_t)g * (N / 2) + (c >> 1)] = packb(v, hi);
                }
            }
        }
    }
}

__global__ __launch_bounds__(256, 3) void gemm1_bin_kernel(
        const float* __restrict__ Av_s, const float* __restrict__ Av_t,
        const unsigned short* __restrict__ WT,
        const float* __restrict__ as_s, const float* __restrict__ ad_s,
        const float* __restrict__ as_t, const float* __restrict__ ad_t,
        unsigned* __restrict__ hb, float* __restrict__ al_s, float* __restrict__ al_d,
        const int* __restrict__ src_s, const int* __restrict__ dst_s,
        const int* __restrict__ src_t, const int* __restrict__ dst_t,
        uint2* __restrict__ region, int* __restrict__ shist) {
    __shared__ __align__(16) unsigned char smem[38912];
    int bid = blockIdx.x;
    if (bid < NBLK) {
        bin_body(bid, smem, src_s, dst_s, src_t, dst_t, region, shist);
    } else {
        gemm1_body(bid - NBLK, smem, Av_s, Av_t, WT, as_s, ad_s, as_t, ad_t, hb, al_s, al_d);
    }
}

// ---- layer-2 GEMM (bf16 A), standalone ----
template <int K, int N>
__global__ __launch_bounds__(256, 3) void gemm2_kernel(
        const unsigned short* __restrict__ Ab_s, const unsigned short* __restrict__ Ab_t,
        const unsigned short* __restrict__ WT,
        const float* __restrict__ as_s, const float* __restrict__ ad_s,
        const float* __restrict__ as_t, const float* __restrict__ ad_t,
        unsigned* __restrict__ hb, float* __restrict__ al_s, float* __restrict__ al_d,
        int nblk) {
    constexpr int NT2 = N / 32;
    constexpr int ROWB = (K / 2) * 2;
    constexpr int CPR = ROWB / 16;
    constexpr int STB = 64 * ROWB;
    constexpr int IPW = (STB / 16) / 256;
    constexpr int SWZ = (CPR - 1) < 15 ? (CPR - 1) : 15;
    constexpr int KBH = (K / 2) / 32;

    __shared__ __align__(16) unsigned char Atile[STB];
    __shared__ float als0[64], ald0[64];

    const int bid = blockIdx.x;
    const int br = (bid >= nblk) ? 1 : 0;
    const int lb = bid - br * nblk;
    const int t = threadIdx.x;
    const int l = t & 63, w = t >> 6;
    const int wm = w >> 1, wn = w & 1;
    const int rl = l & 15, kh = l >> 4;
    const int row0blk = lb * 64;
    const char* Ab = (const char*)(br ? Ab_t : Ab_s);
    const unsigned short* WTb = WT + (size_t)br * N * K;
    const float* asv = br ? as_t : as_s;
    const float* adv = br ? ad_t : ad_s;

    f32x4 acc[2][NT2];
    #pragma unroll
    for (int g = 0; g < 2; g++)
        #pragma unroll
        for (int q = 0; q < NT2; q++) acc[g][q] = (f32x4){0.f, 0.f, 0.f, 0.f};

    #pragma unroll
    for (int h = 0; h < 2; h++) {
        #pragma unroll
        for (int i = 0; i < IPW; i++) {
            int c = (i * 4 + w) * 64 + l;
            int row = c / CPR, jp = c % CPR;
            int jg = jp ^ (row & SWZ);
            int rowg = min(row0blk + row, NN - 1);
            const char* src = Ab + ((size_t)rowg * K + h * (K / 2)) * 2 + jg * 16;
            gload_lds16(src, Atile + c * 16);
        }
        bf16x8 Bv[KBH * NT2];
        #pragma unroll
        for (int kb = 0; kb < KBH; kb++)
            #pragma unroll
            for (int q = 0; q < NT2; q++) {
                int c = wn * (N / 2) + q * 16 + rl;
                Bv[kb * NT2 + q] =
                    *(const bf16x8*)(WTb + (size_t)c * K + h * (K / 2) + kb * 32 + kh * 8);
            }
        __syncthreads();
        #pragma unroll
        for (int kb = 0; kb < KBH; kb++) {
            bf16x8 av[2];
            #pragma unroll
            for (int rg = 0; rg < 2; rg++) {
                int r = wm * 32 + rg * 16 + rl;
                int j = kb * 4 + kh;
                int js = j ^ (r & SWZ);
                av[rg] = *(const bf16x8*)(Atile + r * ROWB + js * 16);
            }
            #pragma unroll
            for (int q = 0; q < NT2; q++) {
                acc[0][q] = __builtin_amdgcn_mfma_f32_16x16x32_bf16(av[0], Bv[kb * NT2 + q], acc[0][q], 0, 0, 0);
                acc[1][q] = __builtin_amdgcn_mfma_f32_16x16x32_bf16(av[1], Bv[kb * NT2 + q], acc[1][q], 0, 0, 0);
            }
        }
        __syncthreads();
    }

    float asr[NT2], adr[NT2];
    #pragma unroll
    for (int q = 0; q < NT2; q++) {
        int c = wn * (N / 2) + q * 16 + rl;
        asr[q] = asv[c];
        adr[q] = adv[c];
    }

    float psA[2][4], pdA[2][4];
    #pragma unroll
    for (int rg = 0; rg < 2; rg++) {
        #pragma unroll
        for (int i = 0; i < 4; i++) {
            float ps = 0.f, pd = 0.f;
            #pragma unroll
            for (int q = 0; q < NT2; q++) {
                float v = acc[rg][q][i];
                ps += v * asr[q];
                pd += v * adr[q];
            }
            #pragma unroll
            for (int off = 1; off < 16; off <<= 1) {
                ps += __shfl_xor(ps, off);
                pd += __shfl_xor(pd, off);
            }
            psA[rg][i] = ps;
            pdA[rg][i] = pd;
        }
    }
    if (wn == 0 && rl == 0) {
        #pragma unroll
        for (int rg = 0; rg < 2; rg++)
            #pragma unroll
            for (int i = 0; i < 4; i++) {
                int rloc = wm * 32 + rg * 16 + kh * 4 + i;
                als0[rloc] = psA[rg][i];
                ald0[rloc] = pdA[rg][i];
            }
    }
    __syncthreads();
    if (wn == 1 && rl == 0) {
        #pragma unroll
        for (int rg = 0; rg < 2; rg++)
            #pragma unroll
            for (int i = 0; i < 4; i++) {
                int rloc = wm * 32 + rg * 16 + kh * 4 + i;
                int rlocal = lb * 64 + rloc;
                if (rlocal < NN) {
                    int g = br * NN + rlocal;
                    al_s[g] = psA[rg][i] + als0[rloc];
                    al_d[g] = pdA[rg][i] + ald0[rloc];
                }
            }
    }
    #pragma unroll
    for (int rg = 0; rg < 2; rg++) {
        #pragma unroll
        for (int i = 0; i < 4; i++) {
            int rlocal = lb * 64 + wm * 32 + rg * 16 + kh * 4 + i;
            bool ok = (rlocal < NN);
            int g = br * NN + rlocal;
            #pragma unroll
            for (int q = 0; q < NT2; q++) {
                float v = acc[rg][q][i];
                float hi = __shfl_xor(v, 1);
                if (ok && !(rl & 1)) {
                    int c = wn * (N / 2) + q * 16 + rl;
                    hb[(size_t)g * (N / 2) + (c >> 1)] = packb(v, hi);
                }
            }
        }
    }
}

// per-bucket totals (one block per bucket, coalesced over chunks)
__global__ void bucket_tot_kernel(const int* __restrict__ shist, int* __restrict__ btot) {
    __shared__ int red[256];
    const int k = blockIdx.x, t = threadIdx.x;
    int s = 0;
    for (int b = t; b < NBLK; b += 256)
        s += shist[(k + 1) * NBLK + b] - shist[k * NBLK + b];
    red[t] = s;
    __syncthreads();
    for (int off = 128; off > 0; off >>= 1) {
        if (t < off) red[t] += red[t + off];
        __syncthreads();
    }
    if (t == 0) btot[k] = red[0];
}

// pass B: one block per bucket -> prefix from btot + LDS histogram/scan -> rowptr + col
__global__ __launch_bounds__(256) void csr_bucket_kernel(const uint2* __restrict__ region,
                                                         const int* __restrict__ shist,
                                                         const int* __restrict__ btot,
                                                         int* __restrict__ rowptr,
                                                         int* __restrict__ col) {
    __shared__ int deg[512];
    __shared__ int part[256];
    __shared__ int cur[512];
    const int k = blockIdx.x, t = threadIdx.x;
    const int n0 = k * 512;
    const int nloc = min(512, NTOT - n0);
    int bacc = 0;
    for (int i = t; i < NBUK; i += 256)
        if (i < k) bacc += btot[i];
    part[t] = bacc;
    deg[t] = 0; deg[t + 256] = 0;
    __syncthreads();
    for (int off = 128; off > 0; off >>= 1) {
        if (t < off) part[t] += part[t + off];
        __syncthreads();
    }
    const int base = part[0];
    __syncthreads();
    for (int b = t; b < NBLK; b += 256) {
        int s0 = shist[k * NBLK + b], s1 = shist[(k + 1) * NBLK + b];
        for (int i = s0; i < s1; i++) {
            uint2 e = region[(size_t)b * CHUNK + i];
            atomicAdd(&deg[(int)e.y - n0], 1);
        }
    }
    __syncthreads();
    int d0 = deg[2 * t], d1 = deg[2 * t + 1];
    int s = d0 + d1;
    part[t] = s;
    __syncthreads();
    for (int off = 1; off < 256; off <<= 1) {
        int u = (t >= off) ? part[t - off] : 0;
        __syncthreads();
        part[t] += u;
        __syncthreads();
    }
    int ex = part[t] - s;
    cur[2 * t] = ex;
    cur[2 * t + 1] = ex + d0;
    if (2 * t < nloc) rowptr[n0 + 2 * t] = base + ex;
    if (2 * t + 1 < nloc) rowptr[n0 + 2 * t + 1] = base + ex + d0;
    if (t == 0 && n0 + nloc == NTOT) rowptr[NTOT] = base + part[255];
    __syncthreads();
    for (int b = t; b < NBLK; b += 256) {
        int s0 = shist[k * NBLK + b], s1 = shist[(k + 1) * NBLK + b];
        for (int i = s0; i < s1; i++) {
            uint2 e = region[(size_t)b * CHUNK + i];
            int pos = atomicAdd(&cur[(int)e.y - n0], 1);
            col[base + pos] = (int)e.x;
        }
    }
}

// ---------------- GAT aggregate, D=128: 8 edges/wave-pass, packed-f32 accumulate ------
__global__ void gat_gather128_kernel(const int* __restrict__ rowptr, const int* __restrict__ col,
                                     const float* __restrict__ al_s, const float* __restrict__ al_d,
                                     const unsigned* __restrict__ hb,
                                     const float* __restrict__ bias_s,
                                     const float* __restrict__ bias_t,
                                     unsigned* __restrict__ outb) {
    int node = blockIdx.x * 4 + (threadIdx.x >> 6);
    int lane = threadIdx.x & 63;
    if (node >= NTOT) return;
    const float* bias = (node < NN) ? bias_s : bias_t;
    const int slot = lane >> 4, sub = lane & 15;
    const int beg = rowptr[node], end = rowptr[node + 1];
    const float ald = al_d[node];
    const float e_self = leaky(al_s[node] + ald);

    f32x2 acc2[4];
    #pragma unroll
    for (int k = 0; k < 4; k++) acc2[k] = (f32x2){0.f, 0.f};
    float dsum = 0.f;
    for (int base = beg; base < end; base += 64) {
        int i = base + lane;
        float w = 0.f; int s = 0;
        if (i < end) {
            s = col[i];
            w = expf(leaky(al_s[s] + ald));   // no max shift: |e| small, f32-safe
        }
        dsum += w;
        int cnt = min(64, end - base);
        for (int j = 0; j < cnt; j += 8) {
            int idx0 = j + slot, idx1 = j + 4 + slot;
            float w0 = __shfl(w, idx0), w1 = __shfl(w, idx1);
            int s0 = __shfl(s, idx0), s1 = __shfl(s, idx1);
            uint4 v0 = *(const uint4*)(hb + (size_t)s0 * 64 + sub * 4);
            uint4 v1 = *(const uint4*)(hb + (size_t)s1 * 64 + sub * 4);
            f32x2 wp0 = (f32x2){w0, w0}, wp1 = (f32x2){w1, w1};
            pkfma(acc2[0], unpk(v0.x), wp0);
            pkfma(acc2[1], unpk(v0.y), wp0);
            pkfma(acc2[2], unpk(v0.z), wp0);
            pkfma(acc2[3], unpk(v0.w), wp0);
            pkfma(acc2[0], unpk(v1.x), wp1);
            pkfma(acc2[1], unpk(v1.y), wp1);
            pkfma(acc2[2], unpk(v1.z), wp1);
            pkfma(acc2[3], unpk(v1.w), wp1);
        }
    }
    float acc[8];
    #pragma unroll
    for (int k = 0; k < 4; k++) { acc[2 * k] = acc2[k].x; acc[2 * k + 1] = acc2[k].y; }
    #pragma unroll
    for (int k = 0; k < 8; k++) {
        acc[k] += __shfl_xor(acc[k], 16);
        acc[k] += __shfl_xor(acc[k], 32);
    }
    #pragma unroll
    for (int off = 32; off > 0; off >>= 1) dsum += __shfl_xor(dsum, off);

    float wself = expf(e_self);
    dsum += wself;
    float inv = 1.f / dsum;
    if (slot == 0) {
        uint4 sv = *(const uint4*)(hb + (size_t)node * 64 + sub * 4);
        float sf[8] = { b2f_lo(sv.x), b2f_hi(sv.x), b2f_lo(sv.y), b2f_hi(sv.y),
                        b2f_lo(sv.z), b2f_hi(sv.z), b2f_lo(sv.w), b2f_hi(sv.w) };
        float o[8];
        #pragma unroll
        for (int k = 0; k < 8; k++)
            o[k] = bias[sub * 8 + k] + (acc[k] + wself * sf[k]) * inv;
        uint4 r = make_uint4(packb(o[0], o[1]), packb(o[2], o[3]),
                             packb(o[4], o[5]), packb(o[6], o[7]));
        *(uint4*)(outb + (size_t)node * 64 + sub * 4) = r;
    }
}

// ---------------- GAT aggregate, D=64: 8 edges/wave-pass, packed-f32 accumulate -------
__global__ void gat_gather64_kernel(const int* __restrict__ rowptr, const int* __restrict__ col,
                                    const float* __restrict__ al_s, const float* __restrict__ al_d,
                                    const unsigned* __restrict__ hb,
                                    const float* __restrict__ bias_s,
                                    const float* __restrict__ bias_t,
                                    float* __restrict__ out) {
    int node = blockIdx.x * 4 + (threadIdx.x >> 6);
    int lane = threadIdx.x & 63;
    if (node >= NTOT) return;
    const float* bias = (node < NN) ? bias_s : bias_t;
    const int slot = lane >> 4, sub = lane & 15;
    const int beg = rowptr[node], end = rowptr[node + 1];
    const float ald = al_d[node];
    const float e_self = leaky(al_s[node] + ald);

    f32x2 acc2[2];
    acc2[0] = (f32x2){0.f, 0.f};
    acc2[1] = (f32x2){0.f, 0.f};
    float dsum = 0.f;
    for (int base = beg; base < end; base += 64) {
        int i = base + lane;
        float w = 0.f; int s = 0;
        if (i < end) {
            s = col[i];
            w = expf(leaky(al_s[s] + ald));
        }
        dsum += w;
        int cnt = min(64, end - base);
        for (int j = 0; j < cnt; j += 8) {
            int idx0 = j + slot, idx1 = j + 4 + slot;
            float w0 = __shfl(w, idx0), w1 = __shfl(w, idx1);
            int s0 = __shfl(s, idx0), s1 = __shfl(s, idx1);
            uint2 v0 = *(const uint2*)(hb + (size_t)s0 * 32 + sub * 2);
            uint2 v1 = *(const uint2*)(hb + (size_t)s1 * 32 + sub * 2);
            f32x2 wp0 = (f32x2){w0, w0}, wp1 = (f32x2){w1, w1};
            pkfma(acc2[0], unpk(v0.x), wp0);
            pkfma(acc2[1], unpk(v0.y), wp0);
            pkfma(acc2[0], unpk(v1.x), wp1);
            pkfma(acc2[1], unpk(v1.y), wp1);
        }
    }
    float acc[4] = { acc2[0].x, acc2[0].y, acc2[1].x, acc2[1].y };
    #pragma unroll
    for (int k = 0; k < 4; k++) {
        acc[k] += __shfl_xor(acc[k], 16);
        acc[k] += __shfl_xor(acc[k], 32);
    }
    #pragma unroll
    for (int off = 32; off > 0; off >>= 1) dsum += __shfl_xor(dsum, off);

    float wself = expf(e_self);
    dsum += wself;
    float inv = 1.f / dsum;
    if (slot == 0) {
        uint2 sv = *(const uint2*)(hb + (size_t)node * 32 + sub * 2);
        float sf[4] = { b2f_lo(sv.x), b2f_hi(sv.x), b2f_lo(sv.y), b2f_hi(sv.y) };
        float4 o;
        o.x = bias[sub * 4 + 0] + (acc[0] + wself * sf[0]) * inv;
        o.y = bias[sub * 4 + 1] + (acc[1] + wself * sf[1]) * inv;
        o.z = bias[sub * 4 + 2] + (acc[2] + wself * sf[2]) * inv;
        o.w = bias[sub * 4 + 3] + (acc[3] + wself * sf[3]) * inv;
        *(float4*)(out + (size_t)node * 64 + sub * 4) = o;
    }
}

// ---------------- segmented mean pool (with inline boundary search), both branches ----
__global__ void pool_seg_kernel(const float* __restrict__ x,
                                const int* __restrict__ bs, const int* __restrict__ bt,
                                float* __restrict__ pooled_s, float* __restrict__ pooled_t) {
    __shared__ float red[4][64];
    __shared__ int bnd[2];
    int g = blockIdx.x;
    int tb = g >= BB;
    int gb = g - tb * BB;
    const int* batch = tb ? bt : bs;
    float* pooled = tb ? pooled_t : pooled_s;
    int off = tb ? NN : 0;
    if (threadIdx.x < 2) {
        int target = gb + threadIdx.x;
        int lo = 0, hi = NN;
        while (lo < hi) {
            int mid = (lo + hi) >> 1;
            if (batch[mid] < target) lo = mid + 1; else hi = mid;
        }
        bnd[threadIdx.x] = lo;
    }
    __syncthreads();
    int beg = bnd[0], end = bnd[1];
    int lane = threadIdx.x & 63, w = threadIdx.x >> 6;
    float acc = 0.f;
    for (int n = beg + w; n < end; n += 4)
        acc += x[(size_t)(off + n) * 64 + lane];
    red[w][lane] = acc;
    __syncthreads();
    if (w == 0) {
        float s = red[0][lane] + red[1][lane] + red[2][lane] + red[3][lane];
        float cnt = (float)(end - beg);
        pooled[(size_t)gb * 64 + lane] = s / fmaxf(cnt, 1.f);
    }
}

// ---------------- final: sigmoid((xs+xt)@lin_w + lin_b) ----------------
__global__ void final_kernel(const float* __restrict__ ps, const float* __restrict__ pt,
                             const float* __restrict__ lw, const float* __restrict__ lb,
                             float* __restrict__ out) {
    int g = blockIdx.x;
    int c = threadIdx.x;
    if (c >= 27) return;
    float acc = lb[c];
    #pragma unroll 8
    for (int k = 0; k < 64; k++) {
        float xv = ps[g * 64 + k] + pt[g * 64 + k];
        acc += xv * lw[k * 27 + c];
    }
    out[g * 27 + c] = 1.f / (1.f + expf(-acc));
}

extern "C" void kernel_launch(void* const* d_in, const int* in_sizes, int n_in,
                              void* d_out, int out_size, void* d_ws, size_t ws_size,
                              hipStream_t stream) {
    const float* x_s = (const float*)d_in[0];
    const float* x_t = (const float*)d_in[1];
    const int* ei_s = (const int*)d_in[2];
    const int* ei_t = (const int*)d_in[3];
    const int* xs_batch = (const int*)d_in[4];
    const int* xt_batch = (const int*)d_in[5];
    const float* W_s1 = (const float*)d_in[6];
    const float* a_src_s1 = (const float*)d_in[7];
    const float* a_dst_s1 = (const float*)d_in[8];
    const float* b_s1 = (const float*)d_in[9];
    const float* W_s2 = (const float*)d_in[10];
    const float* a_src_s2 = (const float*)d_in[11];
    const float* a_dst_s2 = (const float*)d_in[12];
    const float* b_s2 = (const float*)d_in[13];
    const float* W_t1 = (const float*)d_in[14];
    const float* a_src_t1 = (const float*)d_in[15];
    const float* a_dst_t1 = (const float*)d_in[16];
    const float* b_t1 = (const float*)d_in[17];
    const float* W_t2 = (const float*)d_in[18];
    const float* a_src_t2 = (const float*)d_in[19];
    const float* a_dst_t2 = (const float*)d_in[20];
    const float* b_t2 = (const float*)d_in[21];
    const float* lin_w = (const float*)d_in[22];
    const float* lin_b = (const float*)d_in[23];
    float* out = (float*)d_out;

    // workspace carve-up (dword units)
    unsigned* hb = (unsigned*)d_ws;                        // NTOT*64 dw (51.2 MB)
    unsigned* out1b = hb + (size_t)NTOT * 64;              // NTOT*64 dw (51.2 MB)
    float* out2 = (float*)out1b;                           // alias (used after gemm2)
    uint2* region = (uint2*)(out1b + (size_t)NTOT * 64);   // NBLK*CHUNK uint2 (25.6 MB)
    int* col = (int*)(region + (size_t)NBLK * CHUNK);      // ETOT
    float* al_s = (float*)(col + ETOT);                    // NTOT
    float* al_d = al_s + NTOT;                             // NTOT
    float* pooled_s = al_d + NTOT;                         // BB*64
    float* pooled_t = pooled_s + (size_t)BB * 64;          // BB*64
    unsigned short* WT1 = (unsigned short*)(pooled_t + (size_t)BB * 64);  // 2*128*256
    unsigned short* WT2 = WT1 + 2 * 256 * 128;             // 2*64*128
    int* rowptr = (int*)(WT2 + 2 * 128 * 64);              // NTOT+1
    int* shist = rowptr + NTOT + 1;                        // (NBUK+1)*NBLK
    int* btot = shist + (NBUK + 1) * NBLK;                 // NBUK

    const int* src_s = ei_s;
    const int* dst_s = ei_s + EE;
    const int* src_t = ei_t;
    const int* dst_t = ei_t + EE;

    // ----- W^T casts (both layers, one kernel) -----
    wt_all_kernel<<<(2 * 256 * 128 + 2 * 128 * 64 + 255) / 256, 256, 0, stream>>>(
        W_s1, W_t1, W_s2, W_t2, WT1, WT2);

    // ----- fused: bin_sort (CSR pass A) + layer-1 GEMM -----
    gemm1_bin_kernel<<<NBLK + 2 * GB, 256, 0, stream>>>(
        x_s, x_t, WT1, a_src_s1, a_dst_s1, a_src_t1, a_dst_t1, hb, al_s, al_d,
        src_s, dst_s, src_t, dst_t, region, shist);

    // ----- CSR pass B -----
    bucket_tot_kernel<<<NBUK, 256, 0, stream>>>(shist, btot);
    csr_bucket_kernel<<<NBUK, 256, 0, stream>>>(region, shist, btot, rowptr, col);

    // ----- layer 1 gather -----
    gat_gather128_kernel<<<(NTOT + 3) / 4, 256, 0, stream>>>(
        rowptr, col, al_s, al_d, hb, b_s1, b_t1, out1b);

    // ----- layer 2 -----
    gemm2_kernel<128, 64><<<2 * GB, 256, 0, stream>>>(
        (const unsigned short*)out1b, (const unsigned short*)out1b + (size_t)NN * 128, WT2,
        a_src_s2, a_dst_s2, a_src_t2, a_dst_t2, hb, al_s, al_d, GB);
    gat_gather64_kernel<<<(NTOT + 3) / 4, 256, 0, stream>>>(
        rowptr, col, al_s, al_d, hb, b_s2, b_t2, out2);

    // ----- pool + head -----
    pool_seg_kernel<<<2 * BB, 256, 0, stream>>>(out2, xs_batch, xt_batch, pooled_s, pooled_t);
    final_kernel<<<BB, 32, 0, stream>>>(pooled_s, pooled_t, lin_w, lin_b, out);
}